// Round 22
// baseline (28.923 us; speedup 1.0000x reference)
//
#include <hip/hip_runtime.h>
#include <hip/hip_bf16.h>

// Problem constants (from reference)
#define B 8
#define C 64
#define H 64
#define W 64
#define K 5
#define PAD 2
#define HW (H * W)          // 4096
#define CHW (C * HW)        // 262144
#define TOT (B * CHW)       // 2097152

// attn tiling (v10): block = 16-row tile, staged once (20 rows), computed in
// TWO 8-row passes of 2 px/thread; 2048 blocks = exactly 8/CU = 1 round.
#define TROWS 16
#define SROWS (TROWS + 2 * PAD)   // 20 staged rows
#define SCOLS 72                  // 64 + 2*PAD padded to 72 (16B row align)

#define LOG2E 1.44269504088896340736f

typedef __attribute__((ext_vector_type(8))) short short8;   // 8 bf16 = 4 VGPR
typedef __attribute__((ext_vector_type(4))) float f32x4;    // mfma accum

// native bf16 conversion (RNE; pairs lower to v_cvt_pk_bf16_f32)
__device__ inline unsigned short f2bf(float f) {
    __hip_bfloat16 h = __float2bfloat16(f);
    return *(unsigned short*)&h;
}
__device__ inline float bf2f(unsigned short u) {
    return __uint_as_float(((unsigned)u) << 16);
}

// raw v_exp_f32 (single instruction; inputs in [-40,40])
__device__ inline float fast_exp2(float x) {
    return __builtin_amdgcn_exp2f(x);
}

// ---------------------------------------------------------------------------
// Pass 1 (v10): qkv MFMA GEMM — byte-identical to r17 (best config).
// ---------------------------------------------------------------------------
__global__ __launch_bounds__(256) void qkv_mfma(
    const float* __restrict__ x,
    const float* __restrict__ Wq,
    const float* __restrict__ Wk,
    const float* __restrict__ Wv,
    float* __restrict__ qb, float* __restrict__ kb, float* __restrict__ vb)
{
    __shared__ unsigned short sxh[32][72];   // [n][k], 4.6 KB
    __shared__ unsigned short sxl[32][72];

    const int bid = blockIdx.x;
    const int b   = bid & 7;             // XCD co-residency: batch = XCD
    const int n0  = (bid >> 3) * 32;     // hw base (128 chunks per batch)
    const int t   = threadIdx.x;

    const float* xb = x + b * CHW;
#pragma unroll
    for (int i = 0; i < 2; ++i) {
        const int flat = t + i * 256;        // 0..511
        const int k    = flat >> 3;          // 8 float4 per k-row of 32
        const int n4   = (flat & 7) << 2;
        const float4 v = *(const float4*)(xb + k * HW + n0 + n4);
        const float vv[4] = {v.x, v.y, v.z, v.w};
#pragma unroll
        for (int j = 0; j < 4; ++j) {
            const unsigned short h = f2bf(vv[j]);
            sxh[n4 + j][k] = h;
            sxl[n4 + j][k] = f2bf(vv[j] - bf2f(h));
        }
    }
    __syncthreads();

    const int lane = t & 63;
    const int wv   = __builtin_amdgcn_readfirstlane(t >> 6);  // wave id 0..3
    const int lr   = lane & 15;          // tile row (A) / col (B,D)
    const int lk   = (lane >> 4) * 8;    // k-group base

    short8 ah[3][2], al[3][2];
#pragma unroll
    for (int ot = 0; ot < 3; ++ot) {
        const int tile = wv * 3 + ot;            // 0..11
        const int m    = tile >> 2;              // 0=q,1=k,2=v
        const int ol0  = (tile & 3) * 16;        // o base within matrix
        const float* Wm = (m == 0) ? Wq : (m == 1) ? Wk : Wv;
        const float* wrow = Wm + (ol0 + lr) * 64;
#pragma unroll
        for (int ks = 0; ks < 2; ++ks) {
            const float4 w0 = *(const float4*)(wrow + lk + ks * 32);
            const float4 w1 = *(const float4*)(wrow + lk + ks * 32 + 4);
            const float wv8[8] = {w0.x, w0.y, w0.z, w0.w,
                                  w1.x, w1.y, w1.z, w1.w};
            short8 hi, lo;
#pragma unroll
            for (int j = 0; j < 8; ++j) {
                const unsigned short hh = f2bf(wv8[j]);
                hi[j] = (short)hh;
                lo[j] = (short)f2bf(wv8[j] - bf2f(hh));
            }
            ah[ot][ks] = hi;
            al[ot][ks] = lo;
        }
    }

    f32x4 acc[3][2];
#pragma unroll
    for (int ot = 0; ot < 3; ++ot)
#pragma unroll
        for (int nt = 0; nt < 2; ++nt) acc[ot][nt] = (f32x4)0.f;

#pragma unroll
    for (int nt = 0; nt < 2; ++nt) {
        const short8 bh0 = *(const short8*)&sxh[nt * 16 + lr][lk];
        const short8 bh1 = *(const short8*)&sxh[nt * 16 + lr][32 + lk];
        const short8 bl0 = *(const short8*)&sxl[nt * 16 + lr][lk];
        const short8 bl1 = *(const short8*)&sxl[nt * 16 + lr][32 + lk];
#pragma unroll
        for (int ot = 0; ot < 3; ++ot) {
            f32x4 d = acc[ot][nt];
            d = __builtin_amdgcn_mfma_f32_16x16x32_bf16(ah[ot][0], bh0, d, 0, 0, 0);
            d = __builtin_amdgcn_mfma_f32_16x16x32_bf16(ah[ot][1], bh1, d, 0, 0, 0);
            d = __builtin_amdgcn_mfma_f32_16x16x32_bf16(ah[ot][0], bl0, d, 0, 0, 0);
            d = __builtin_amdgcn_mfma_f32_16x16x32_bf16(ah[ot][1], bl1, d, 0, 0, 0);
            d = __builtin_amdgcn_mfma_f32_16x16x32_bf16(al[ot][0], bh0, d, 0, 0, 0);
            d = __builtin_amdgcn_mfma_f32_16x16x32_bf16(al[ot][1], bh1, d, 0, 0, 0);
            acc[ot][nt] = d;
        }
    }

#pragma unroll
    for (int ot = 0; ot < 3; ++ot) {
        const int tile = wv * 3 + ot;
        const int m    = tile >> 2;
        const int ol0  = (tile & 3) * 16;
        float* ob = (m == 0) ? qb : (m == 1) ? kb : vb;
        float* basep = ob + b * CHW + ol0 * HW + n0;
#pragma unroll
        for (int nt = 0; nt < 2; ++nt)
#pragma unroll
            for (int r = 0; r < 4; ++r) {
                const int orow = (lane >> 4) * 4 + r;
                basep[orow * HW + nt * 16 + lr] = acc[ot][nt][r];
            }
    }
}

// ---------------------------------------------------------------------------
// Pass 2 (v10): attn — 16-row tile staged ONCE (r17's cheap pow-2 stage,
// 1.25x halo), computed in TWO 8-row passes of 2 px/thread (r21's low-
// pressure body).  2048 blocks = exactly 8 blocks/CU = ONE resident round
// (r21's 4096 blocks ran 2 rounds with 1.5x halo).  ONE barrier per block:
// both passes read the same read-only staged buffer.  q loads for both
// passes hoisted above the stage.
// ---------------------------------------------------------------------------
__global__ __launch_bounds__(256) void attn_kernel(
    const float* __restrict__ qb,
    const float* __restrict__ kb,
    const float* __restrict__ vb,
    const float* __restrict__ rel_h,
    const float* __restrict__ rel_w,
    float* __restrict__ out)
{
    __shared__ __align__(16) float sk[SROWS][SCOLS];   // 5.76 KB
    __shared__ __align__(16) float sv[SROWS][SCOLS];   // 5.76 KB

    const int bid = blockIdx.x;
    const int b   = bid & 7;           // XCD co-residency: batch = XCD
    const int u   = bid >> 3;          // 0..255: chan*4 + rowtile
    const int c   = u >> 2;
    const int pl  = b * C + c;
    const int h0  = (u & 3) * TROWS;
    const int t   = threadIdx.x;

    const int lrt = t >> 5;            // pass-local row 0..7
    const int w0  = (t & 31) << 1;     // col base 0,2,..,62 (2 px)

    // hoisted q loads for both passes: latency hides under the stage
    const float* qbp = qb + pl * HW + w0;
    const float2 qA = *(const float2*)(qbp + (h0 + lrt) * W);
    const float2 qB = *(const float2*)(qbp + (h0 + 8 + lrt) * W);

    const float* kp = kb + pl * HW;
    const float* vp = vb + pl * HW;

    // ---- stage interior: 2 planes * 640 f2 slots (pow-2 mapping, 5/thr) ----
#pragma unroll
    for (int i = 0; i < 5; ++i) {
        const int s  = t + i * 256;          // 0..1279
        const int p  = (s >= 640);
        const int s2 = p ? s - 640 : s;
        const int row = s2 >> 5;             // 0..19
        const int c2  = s2 & 31;             // f2 slot within row
        const int g   = h0 + row - PAD;      // global row
        float2 val = make_float2(0.f, 0.f);
        if ((unsigned)g < (unsigned)H)
            val = *(const float2*)((p ? vp : kp) + g * W + c2 * 2);
        float* dst = (p ? &sv[0][0] : &sk[0][0]) + row * SCOLS + 2 + c2 * 2;
        *(float2*)dst = val;
    }
    // ---- halo ring zero: cols {0,1} and {66..71} of all 20 rows ----
    if (t < 160) {
        const int p   = (t >= 80);
        const int s   = p ? t - 80 : t;
        const int row = s >> 2;              // 0..19
        const int e   = s & 3;               // 0 -> col 0; 1..3 -> 66,68,70
        const int col = (e == 0) ? 0 : (64 + 2 * e);
        float* dst = (p ? &sv[0][0] : &sk[0][0]) + row * SCOLS + col;
        *(float2*)dst = make_float2(0.f, 0.f);
    }
    __syncthreads();

    const bool is_h = (c < (C / 2));
    const float* rp = is_h ? (rel_h + c * K) : (rel_w + (c - C / 2) * K);
    float r[K];
#pragma unroll
    for (int u2 = 0; u2 < K; ++u2) r[u2] = rp[u2];

    // one 8-row pass: 2 px/thread at (lr, w0/w0+1); tap j for px reads LDS
    // col (w0+px)+j (padded col = global col + 2 handled by stage layout)
    auto pass = [&](const float2 qv, const int lr, float* __restrict__ op) {
        const float qe0 = qv.x * LOG2E;
        const float qe1 = qv.y * LOG2E;
        float den0 = 0.f, den1 = 0.f, num0 = 0.f, num1 = 0.f;
        if (is_h) {
#pragma unroll
            for (int i = 0; i < K; ++i) {
                const float2 k0 = *(const float2*)&sk[lr + i][w0];
                const float2 k1 = *(const float2*)&sk[lr + i][w0 + 2];
                const float2 k2 = *(const float2*)&sk[lr + i][w0 + 4];
                const float2 v0 = *(const float2*)&sv[lr + i][w0];
                const float2 v1 = *(const float2*)&sv[lr + i][w0 + 2];
                const float2 v2 = *(const float2*)&sv[lr + i][w0 + 4];
                const float kt[6] = {k0.x, k0.y, k1.x, k1.y, k2.x, k2.y};
                const float vt[6] = {v0.x, v0.y, v1.x, v1.y, v2.x, v2.y};
                const float qri0 = qe0 * r[i];
                const float qri1 = qe1 * r[i];
#pragma unroll
                for (int j = 0; j < K; ++j) {
                    const float e0 = fast_exp2(fmaf(qe0, kt[j], qri0));
                    den0 += e0;
                    num0 = fmaf(e0, vt[j], num0);
                    const float e1 = fast_exp2(fmaf(qe1, kt[j + 1], qri1));
                    den1 += e1;
                    num1 = fmaf(e1, vt[j + 1], num1);
                }
            }
        } else {
#pragma unroll
            for (int i = 0; i < K; ++i) {
                const float2 k0 = *(const float2*)&sk[lr + i][w0];
                const float2 k1 = *(const float2*)&sk[lr + i][w0 + 2];
                const float2 k2 = *(const float2*)&sk[lr + i][w0 + 4];
                const float2 v0 = *(const float2*)&sv[lr + i][w0];
                const float2 v1 = *(const float2*)&sv[lr + i][w0 + 2];
                const float2 v2 = *(const float2*)&sv[lr + i][w0 + 4];
                const float kt[6] = {k0.x, k0.y, k1.x, k1.y, k2.x, k2.y};
                const float vt[6] = {v0.x, v0.y, v1.x, v1.y, v2.x, v2.y};
#pragma unroll
                for (int j = 0; j < K; ++j) {
                    const float qrj0 = qe0 * r[j];
                    const float qrj1 = qe1 * r[j];
                    const float e0 = fast_exp2(fmaf(qe0, kt[j], qrj0));
                    den0 += e0;
                    num0 = fmaf(e0, vt[j], num0);
                    const float e1 = fast_exp2(fmaf(qe1, kt[j + 1], qrj1));
                    den1 += e1;
                    num1 = fmaf(e1, vt[j + 1], num1);
                }
            }
        }
        float2 o;
        o.x = num0 * __builtin_amdgcn_rcpf(den0);
        o.y = num1 * __builtin_amdgcn_rcpf(den1);
        *(float2*)op = o;
    };

    float* outp = out + pl * HW + w0;
    pass(qA, lrt,     outp + (h0 + lrt) * W);
    pass(qB, lrt + 8, outp + (h0 + 8 + lrt) * W);
}

// ---------------------------------------------------------------------------
extern "C" void kernel_launch(void* const* d_in, const int* in_sizes, int n_in,
                              void* d_out, int out_size, void* d_ws, size_t ws_size,
                              hipStream_t stream)
{
    const float* x     = (const float*)d_in[0];
    const float* Wq    = (const float*)d_in[1];
    const float* Wk    = (const float*)d_in[2];
    const float* Wv    = (const float*)d_in[3];
    const float* rel_h = (const float*)d_in[4];
    const float* rel_w = (const float*)d_in[5];

    float* qb = (float*)d_ws;        // [B,C,64,64]  8 MB
    float* kb = qb + TOT;            // [B,C,64,64]  8 MB
    float* vb = kb + TOT;            // [B,C,64,64]  8 MB

    qkv_mfma<<<B * 128, 256, 0, stream>>>(x, Wq, Wk, Wv, qb, kb, vb);

    attn_kernel<<<B * C * 4, 256, 0, stream>>>(qb, kb, vb, rel_h, rel_w,
                                               (float*)d_out);
}

// Round 23
// 26.943 us; speedup vs baseline: 1.0735x; 1.0735x over previous
//
#include <hip/hip_runtime.h>
#include <hip/hip_bf16.h>

// Problem constants (from reference)
#define B 8
#define C 64
#define H 64
#define W 64
#define K 5
#define PAD 2
#define HW (H * W)          // 4096
#define CHW (C * HW)        // 262144
#define TOT (B * CHW)       // 2097152

// attn tiling (r21 shape): block = 8 rows x 64 cols; 2 px/thread; 4096 blocks
#define TROWS3 8
#define SROWS3 (TROWS3 + 2 * PAD)  // 12 staged rows
#define SCOLS 72                   // 64 + 2*PAD padded to 72 (16B row align)

#define LOG2E 1.44269504088896340736f

typedef __attribute__((ext_vector_type(8))) short short8;   // 8 bf16 = 4 VGPR
typedef __attribute__((ext_vector_type(4))) float f32x4;    // mfma accum

// native bf16 conversion (RNE; pairs lower to v_cvt_pk_bf16_f32)
__device__ inline unsigned short f2bf(float f) {
    __hip_bfloat16 h = __float2bfloat16(f);
    return *(unsigned short*)&h;
}
__device__ inline float bf2f(unsigned short u) {
    return __uint_as_float(((unsigned)u) << 16);
}

// raw v_exp_f32 (single instruction; inputs in [-40,40])
__device__ inline float fast_exp2(float x) {
    return __builtin_amdgcn_exp2f(x);
}

// ---------------------------------------------------------------------------
// Pass 1 (v11): qkv MFMA GEMM — r17 structure with A-FRAGMENT PREP HOISTED
// ABOVE THE STAGE: the 12 float4 W-loads + ~150 cvt VALU now execute under
// the x stage-load latency instead of serializing after the barrier.
// Everything else (tiling, fragment maps, MFMA order, epilogue) identical.
// ---------------------------------------------------------------------------
__global__ __launch_bounds__(256) void qkv_mfma(
    const float* __restrict__ x,
    const float* __restrict__ Wq,
    const float* __restrict__ Wk,
    const float* __restrict__ Wv,
    float* __restrict__ qb, float* __restrict__ kb, float* __restrict__ vb)
{
    __shared__ unsigned short sxh[32][72];   // [n][k], 4.6 KB
    __shared__ unsigned short sxl[32][72];

    const int bid = blockIdx.x;
    const int b   = bid & 7;             // XCD co-residency: batch = XCD
    const int n0  = (bid >> 3) * 32;     // hw base (128 chunks per batch)
    const int t   = threadIdx.x;

    const int lane = t & 63;
    const int wv   = __builtin_amdgcn_readfirstlane(t >> 6);  // wave id 0..3
    const int lr   = lane & 15;          // tile row (A) / col (B,D)
    const int lk   = (lane >> 4) * 8;    // k-group base

    // ---- A fragments FIRST (overlaps the x stage-load latency below) ----
    short8 ah[3][2], al[3][2];
#pragma unroll
    for (int ot = 0; ot < 3; ++ot) {
        const int tile = wv * 3 + ot;            // 0..11
        const int m    = tile >> 2;              // 0=q,1=k,2=v
        const int ol0  = (tile & 3) * 16;        // o base within matrix
        const float* Wm = (m == 0) ? Wq : (m == 1) ? Wk : Wv;
        const float* wrow = Wm + (ol0 + lr) * 64;
#pragma unroll
        for (int ks = 0; ks < 2; ++ks) {
            const float4 w0 = *(const float4*)(wrow + lk + ks * 32);
            const float4 w1 = *(const float4*)(wrow + lk + ks * 32 + 4);
            const float wv8[8] = {w0.x, w0.y, w0.z, w0.w,
                                  w1.x, w1.y, w1.z, w1.w};
            short8 hi, lo;
#pragma unroll
            for (int j = 0; j < 8; ++j) {
                const unsigned short hh = f2bf(wv8[j]);
                hi[j] = (short)hh;
                lo[j] = (short)f2bf(wv8[j] - bf2f(hh));
            }
            ah[ot][ks] = hi;
            al[ot][ks] = lo;
        }
    }

    // ---- stage + convert x: 512 float4, 2 per thread, coalesced ----
    const float* xb = x + b * CHW;
#pragma unroll
    for (int i = 0; i < 2; ++i) {
        const int flat = t + i * 256;        // 0..511
        const int k    = flat >> 3;          // 8 float4 per k-row of 32
        const int n4   = (flat & 7) << 2;
        const float4 v = *(const float4*)(xb + k * HW + n0 + n4);
        const float vv[4] = {v.x, v.y, v.z, v.w};
#pragma unroll
        for (int j = 0; j < 4; ++j) {
            const unsigned short h = f2bf(vv[j]);
            sxh[n4 + j][k] = h;
            sxl[n4 + j][k] = f2bf(vv[j] - bf2f(h));
        }
    }
    __syncthreads();

    f32x4 acc[3][2];
#pragma unroll
    for (int ot = 0; ot < 3; ++ot)
#pragma unroll
        for (int nt = 0; nt < 2; ++nt) acc[ot][nt] = (f32x4)0.f;

#pragma unroll
    for (int nt = 0; nt < 2; ++nt) {
        const short8 bh0 = *(const short8*)&sxh[nt * 16 + lr][lk];
        const short8 bh1 = *(const short8*)&sxh[nt * 16 + lr][32 + lk];
        const short8 bl0 = *(const short8*)&sxl[nt * 16 + lr][lk];
        const short8 bl1 = *(const short8*)&sxl[nt * 16 + lr][32 + lk];
#pragma unroll
        for (int ot = 0; ot < 3; ++ot) {
            f32x4 d = acc[ot][nt];
            d = __builtin_amdgcn_mfma_f32_16x16x32_bf16(ah[ot][0], bh0, d, 0, 0, 0);
            d = __builtin_amdgcn_mfma_f32_16x16x32_bf16(ah[ot][1], bh1, d, 0, 0, 0);
            d = __builtin_amdgcn_mfma_f32_16x16x32_bf16(ah[ot][0], bl0, d, 0, 0, 0);
            d = __builtin_amdgcn_mfma_f32_16x16x32_bf16(ah[ot][1], bl1, d, 0, 0, 0);
            d = __builtin_amdgcn_mfma_f32_16x16x32_bf16(al[ot][0], bh0, d, 0, 0, 0);
            d = __builtin_amdgcn_mfma_f32_16x16x32_bf16(al[ot][1], bh1, d, 0, 0, 0);
            acc[ot][nt] = d;
        }
    }

#pragma unroll
    for (int ot = 0; ot < 3; ++ot) {
        const int tile = wv * 3 + ot;
        const int m    = tile >> 2;
        const int ol0  = (tile & 3) * 16;
        float* ob = (m == 0) ? qb : (m == 1) ? kb : vb;
        float* basep = ob + b * CHW + ol0 * HW + n0;
#pragma unroll
        for (int nt = 0; nt < 2; ++nt)
#pragma unroll
            for (int r = 0; r < 4; ++r) {
                const int orow = (lane >> 4) * 4 + r;
                basep[orow * HW + nt * 16 + lr] = acc[ot][nt][r];
            }
    }
}

// ---------------------------------------------------------------------------
// Pass 2 (v11): attn — r21 structure (best: 27.5 us) with FLOAT4 STAGE:
// 384 float4 slots (1.5/thread) instead of 768 float2 (3/thread) — half the
// global-load instructions; each written as two aligned float2s into the
// identical LDS layout.  Compute loop byte-identical to r21.
// ---------------------------------------------------------------------------
__global__ __launch_bounds__(256) void attn_kernel(
    const float* __restrict__ qb,
    const float* __restrict__ kb,
    const float* __restrict__ vb,
    const float* __restrict__ rel_h,
    const float* __restrict__ rel_w,
    float* __restrict__ out)
{
    __shared__ __align__(16) float sk[SROWS3][SCOLS];   // 3.5 KB
    __shared__ __align__(16) float sv[SROWS3][SCOLS];   // 3.5 KB

    const int bid = blockIdx.x;
    const int b   = bid & 7;           // XCD co-residency: batch = XCD
    const int u   = bid >> 3;          // 0..511: c*8 + rowtile
    const int c   = u >> 3;
    const int pl  = b * C + c;
    const int h0  = (u & 7) * TROWS3;
    const int t   = threadIdx.x;

    const int lr = t >> 5;             // local row 0..7
    const int w0 = (t & 31) << 1;      // col base 0,2,..,62 (2 px)
    const int h  = h0 + lr;

    // hoisted q load: latency hides under the stage
    const float2 qv = *(const float2*)(qb + pl * HW + h * W + w0);

    const float* kp = kb + pl * HW;
    const float* vp = vb + pl * HW;

    // ---- stage interior: 2 planes * (12 rows x 16 f4) = 384 slots ----
#pragma unroll
    for (int i = 0; i < 2; ++i) {
        const int s = t + i * 256;           // 0..511
        if (s < 2 * SROWS3 * 16) {           // 384
            const int p   = (s >= SROWS3 * 16);
            const int s2  = p ? s - SROWS3 * 16 : s;
            const int row = s2 >> 4;         // 0..11
            const int c4  = s2 & 15;         // f4 slot within row
            const int g   = h0 + row - PAD;  // global row
            float4 val = make_float4(0.f, 0.f, 0.f, 0.f);
            if ((unsigned)g < (unsigned)H)
                val = *(const float4*)((p ? vp : kp) + g * W + c4 * 4);
            float* dst = (p ? &sv[0][0] : &sk[0][0]) + row * SCOLS + 2 + c4 * 4;
            *(float2*)dst       = make_float2(val.x, val.y);
            *(float2*)(dst + 2) = make_float2(val.z, val.w);
        }
    }
    // ---- halo ring zero: cols {0,1},{66..71} of all 12 rows, both planes ----
    if (t < 2 * SROWS3 * 4) {          // 96
        const int p   = (t >= SROWS3 * 4);
        const int s   = p ? t - SROWS3 * 4 : t;
        const int row = s >> 2;              // 0..11
        const int e   = s & 3;               // 0 -> col 0; 1..3 -> 66,68,70
        const int col = (e == 0) ? 0 : (64 + 2 * e);
        float* dst = (p ? &sv[0][0] : &sk[0][0]) + row * SCOLS + col;
        *(float2*)dst = make_float2(0.f, 0.f);
    }
    __syncthreads();

    const float qe[2] = {qv.x * LOG2E, qv.y * LOG2E};

    const bool is_h = (c < (C / 2));
    const float* rp = is_h ? (rel_h + c * K) : (rel_w + (c - C / 2) * K);
    float r[K];
#pragma unroll
    for (int u2 = 0; u2 < K; ++u2) r[u2] = rp[u2];

    float den[2] = {0.f, 0.f};
    float num[2] = {0.f, 0.f};

    // px at global col w0+px; tap j reads LDS col (w0+px)+j  (interior at +2)
    if (is_h) {
#pragma unroll
        for (int i = 0; i < K; ++i) {
            const float2 k0 = *(const float2*)&sk[lr + i][w0];
            const float2 k1 = *(const float2*)&sk[lr + i][w0 + 2];
            const float2 k2 = *(const float2*)&sk[lr + i][w0 + 4];
            const float2 v0 = *(const float2*)&sv[lr + i][w0];
            const float2 v1 = *(const float2*)&sv[lr + i][w0 + 2];
            const float2 v2 = *(const float2*)&sv[lr + i][w0 + 4];
            const float kt[6] = {k0.x, k0.y, k1.x, k1.y, k2.x, k2.y};
            const float vt[6] = {v0.x, v0.y, v1.x, v1.y, v2.x, v2.y};
            const float qri0 = qe[0] * r[i];
            const float qri1 = qe[1] * r[i];
#pragma unroll
            for (int j = 0; j < K; ++j) {
                const float e0 = fast_exp2(fmaf(qe[0], kt[j], qri0));
                den[0] += e0;
                num[0] = fmaf(e0, vt[j], num[0]);
                const float e1 = fast_exp2(fmaf(qe[1], kt[j + 1], qri1));
                den[1] += e1;
                num[1] = fmaf(e1, vt[j + 1], num[1]);
            }
        }
    } else {
#pragma unroll
        for (int i = 0; i < K; ++i) {
            const float2 k0 = *(const float2*)&sk[lr + i][w0];
            const float2 k1 = *(const float2*)&sk[lr + i][w0 + 2];
            const float2 k2 = *(const float2*)&sk[lr + i][w0 + 4];
            const float2 v0 = *(const float2*)&sv[lr + i][w0];
            const float2 v1 = *(const float2*)&sv[lr + i][w0 + 2];
            const float2 v2 = *(const float2*)&sv[lr + i][w0 + 4];
            const float kt[6] = {k0.x, k0.y, k1.x, k1.y, k2.x, k2.y};
            const float vt[6] = {v0.x, v0.y, v1.x, v1.y, v2.x, v2.y};
#pragma unroll
            for (int j = 0; j < K; ++j) {
                const float qrj0 = qe[0] * r[j];
                const float qrj1 = qe[1] * r[j];
                const float e0 = fast_exp2(fmaf(qe[0], kt[j], qrj0));
                den[0] += e0;
                num[0] = fmaf(e0, vt[j], num[0]);
                const float e1 = fast_exp2(fmaf(qe[1], kt[j + 1], qrj1));
                den[1] += e1;
                num[1] = fmaf(e1, vt[j + 1], num[1]);
            }
        }
    }

    float2 o;
    o.x = num[0] * __builtin_amdgcn_rcpf(den[0]);
    o.y = num[1] * __builtin_amdgcn_rcpf(den[1]);
    *(float2*)(out + pl * HW + h * W + w0) = o;
}

// ---------------------------------------------------------------------------
extern "C" void kernel_launch(void* const* d_in, const int* in_sizes, int n_in,
                              void* d_out, int out_size, void* d_ws, size_t ws_size,
                              hipStream_t stream)
{
    const float* x     = (const float*)d_in[0];
    const float* Wq    = (const float*)d_in[1];
    const float* Wk    = (const float*)d_in[2];
    const float* Wv    = (const float*)d_in[3];
    const float* rel_h = (const float*)d_in[4];
    const float* rel_w = (const float*)d_in[5];

    float* qb = (float*)d_ws;        // [B,C,64,64]  8 MB
    float* kb = qb + TOT;            // [B,C,64,64]  8 MB
    float* vb = kb + TOT;            // [B,C,64,64]  8 MB

    qkv_mfma<<<B * 128, 256, 0, stream>>>(x, Wq, Wk, Wv, qb, kb, vb);

    attn_kernel<<<B * C * 8, 256, 0, stream>>>(qb, kb, vb, rel_h, rel_w,
                                               (float*)d_out);
}

// Round 25
// 26.229 us; speedup vs baseline: 1.1027x; 1.0272x over previous
//
#include <hip/hip_runtime.h>
#include <hip/hip_bf16.h>

// Problem constants (from reference)
#define B 8
#define C 64
#define H 64
#define W 64
#define K 5
#define PAD 2
#define HW (H * W)          // 4096
#define CHW (C * HW)        // 262144
#define TOT (B * CHW)       // 2097152

// attn tiling (r21 shape): block = 8 rows x 64 cols; 2 px/thread; 4096 blocks
#define TROWS3 8
#define SROWS3 (TROWS3 + 2 * PAD)  // 12 staged rows
#define SCOLS 72                   // 64 + 2*PAD padded to 72 (16B row align)

#define LOG2E 1.44269504088896340736f

typedef __attribute__((ext_vector_type(8))) short short8;   // 8 bf16 = 4 VGPR
typedef __attribute__((ext_vector_type(4))) float f32x4;    // mfma accum
typedef __attribute__((ext_vector_type(2))) float f32x2;    // nt-load/store

// native bf16 conversion (RNE; pairs lower to v_cvt_pk_bf16_f32)
__device__ inline unsigned short f2bf(float f) {
    __hip_bfloat16 h = __float2bfloat16(f);
    return *(unsigned short*)&h;
}
__device__ inline float bf2f(unsigned short u) {
    return __uint_as_float(((unsigned)u) << 16);
}

// raw v_exp_f32 (single instruction; inputs in [-40,40])
__device__ inline float fast_exp2(float x) {
    return __builtin_amdgcn_exp2f(x);
}

// ---------------------------------------------------------------------------
// Pass 1 (v12): qkv MFMA GEMM — r23 structure (A-frag prep hoisted above the
// stage) with ONE change: the q output is PRE-SCALED by log2(e) in the
// epilogue (q is only ever consumed by attn's exp2 path), deleting attn's
// per-thread LOG2E muls.  k/v epilogue unchanged.
// ---------------------------------------------------------------------------
__global__ __launch_bounds__(256) void qkv_mfma(
    const float* __restrict__ x,
    const float* __restrict__ Wq,
    const float* __restrict__ Wk,
    const float* __restrict__ Wv,
    float* __restrict__ qb, float* __restrict__ kb, float* __restrict__ vb)
{
    __shared__ unsigned short sxh[32][72];   // [n][k], 4.6 KB
    __shared__ unsigned short sxl[32][72];

    const int bid = blockIdx.x;
    const int b   = bid & 7;             // XCD co-residency: batch = XCD
    const int n0  = (bid >> 3) * 32;     // hw base (128 chunks per batch)
    const int t   = threadIdx.x;

    const int lane = t & 63;
    const int wv   = __builtin_amdgcn_readfirstlane(t >> 6);  // wave id 0..3
    const int lr   = lane & 15;          // tile row (A) / col (B,D)
    const int lk   = (lane >> 4) * 8;    // k-group base

    // ---- A fragments FIRST (overlaps the x stage-load latency below) ----
    short8 ah[3][2], al[3][2];
#pragma unroll
    for (int ot = 0; ot < 3; ++ot) {
        const int tile = wv * 3 + ot;            // 0..11
        const int m    = tile >> 2;              // 0=q,1=k,2=v
        const int ol0  = (tile & 3) * 16;        // o base within matrix
        const float* Wm = (m == 0) ? Wq : (m == 1) ? Wk : Wv;
        const float* wrow = Wm + (ol0 + lr) * 64;
#pragma unroll
        for (int ks = 0; ks < 2; ++ks) {
            const float4 w0 = *(const float4*)(wrow + lk + ks * 32);
            const float4 w1 = *(const float4*)(wrow + lk + ks * 32 + 4);
            const float wv8[8] = {w0.x, w0.y, w0.z, w0.w,
                                  w1.x, w1.y, w1.z, w1.w};
            short8 hi, lo;
#pragma unroll
            for (int j = 0; j < 8; ++j) {
                const unsigned short hh = f2bf(wv8[j]);
                hi[j] = (short)hh;
                lo[j] = (short)f2bf(wv8[j] - bf2f(hh));
            }
            ah[ot][ks] = hi;
            al[ot][ks] = lo;
        }
    }

    // ---- stage + convert x: 512 float4, 2 per thread, coalesced ----
    const float* xb = x + b * CHW;
#pragma unroll
    for (int i = 0; i < 2; ++i) {
        const int flat = t + i * 256;        // 0..511
        const int k    = flat >> 3;          // 8 float4 per k-row of 32
        const int n4   = (flat & 7) << 2;
        const float4 v = *(const float4*)(xb + k * HW + n0 + n4);
        const float vv[4] = {v.x, v.y, v.z, v.w};
#pragma unroll
        for (int j = 0; j < 4; ++j) {
            const unsigned short h = f2bf(vv[j]);
            sxh[n4 + j][k] = h;
            sxl[n4 + j][k] = f2bf(vv[j] - bf2f(h));
        }
    }
    __syncthreads();

    f32x4 acc[3][2];
#pragma unroll
    for (int ot = 0; ot < 3; ++ot)
#pragma unroll
        for (int nt = 0; nt < 2; ++nt) acc[ot][nt] = (f32x4)0.f;

#pragma unroll
    for (int nt = 0; nt < 2; ++nt) {
        const short8 bh0 = *(const short8*)&sxh[nt * 16 + lr][lk];
        const short8 bh1 = *(const short8*)&sxh[nt * 16 + lr][32 + lk];
        const short8 bl0 = *(const short8*)&sxl[nt * 16 + lr][lk];
        const short8 bl1 = *(const short8*)&sxl[nt * 16 + lr][32 + lk];
#pragma unroll
        for (int ot = 0; ot < 3; ++ot) {
            f32x4 d = acc[ot][nt];
            d = __builtin_amdgcn_mfma_f32_16x16x32_bf16(ah[ot][0], bh0, d, 0, 0, 0);
            d = __builtin_amdgcn_mfma_f32_16x16x32_bf16(ah[ot][1], bh1, d, 0, 0, 0);
            d = __builtin_amdgcn_mfma_f32_16x16x32_bf16(ah[ot][0], bl0, d, 0, 0, 0);
            d = __builtin_amdgcn_mfma_f32_16x16x32_bf16(ah[ot][1], bl1, d, 0, 0, 0);
            d = __builtin_amdgcn_mfma_f32_16x16x32_bf16(al[ot][0], bh0, d, 0, 0, 0);
            d = __builtin_amdgcn_mfma_f32_16x16x32_bf16(al[ot][1], bh1, d, 0, 0, 0);
            acc[ot][nt] = d;
        }
    }

#pragma unroll
    for (int ot = 0; ot < 3; ++ot) {
        const int tile = wv * 3 + ot;
        const int m    = tile >> 2;
        const int ol0  = (tile & 3) * 16;
        float* ob = (m == 0) ? qb : (m == 1) ? kb : vb;
        const float scale = (m == 0) ? LOG2E : 1.0f;   // q pre-scaled for exp2
        float* basep = ob + b * CHW + ol0 * HW + n0;
#pragma unroll
        for (int nt = 0; nt < 2; ++nt)
#pragma unroll
            for (int r = 0; r < 4; ++r) {
                const int orow = (lane >> 4) * 4 + r;
                basep[orow * HW + nt * 16 + lr] = acc[ot][nt][r] * scale;
            }
    }
}

// ---------------------------------------------------------------------------
// Pass 2 (v12): attn — r23 structure with L2-CAPACITY HINTS:
// out stored via __builtin_nontemporal_store (never re-read; keeps 1 MB/XCD
// of dirty lines out of L2), q loaded via __builtin_nontemporal_load (read
// exactly once; evict-after-read).  Per-XCD working set drops from 5 MB
// (overflows the 4 MB L2 -> HBM writeback churn) to 4 MB (q/k/v + x).
// q arrives pre-scaled by log2(e).  Nontemporal accesses use ext_vector
// f32x2 (clang requires native vector types for the builtin).
// Everything else identical to r23.
// ---------------------------------------------------------------------------
__global__ __launch_bounds__(256) void attn_kernel(
    const float* __restrict__ qb,
    const float* __restrict__ kb,
    const float* __restrict__ vb,
    const float* __restrict__ rel_h,
    const float* __restrict__ rel_w,
    float* __restrict__ out)
{
    __shared__ __align__(16) float sk[SROWS3][SCOLS];   // 3.5 KB
    __shared__ __align__(16) float sv[SROWS3][SCOLS];   // 3.5 KB

    const int bid = blockIdx.x;
    const int b   = bid & 7;           // XCD co-residency: batch = XCD
    const int u   = bid >> 3;          // 0..511: c*8 + rowtile
    const int c   = u >> 3;
    const int pl  = b * C + c;
    const int h0  = (u & 7) * TROWS3;
    const int t   = threadIdx.x;

    const int lr = t >> 5;             // local row 0..7
    const int w0 = (t & 31) << 1;      // col base 0,2,..,62 (2 px)
    const int h  = h0 + lr;

    // hoisted q load (nt: read-once, evict-after-read); pre-scaled by log2e
    const f32x2 qv = __builtin_nontemporal_load(
        (const f32x2*)(qb + pl * HW + h * W + w0));

    const float* kp = kb + pl * HW;
    const float* vp = vb + pl * HW;

    // ---- stage interior: 2 planes * (12 rows x 16 f4) = 384 slots ----
#pragma unroll
    for (int i = 0; i < 2; ++i) {
        const int s = t + i * 256;           // 0..511
        if (s < 2 * SROWS3 * 16) {           // 384
            const int p   = (s >= SROWS3 * 16);
            const int s2  = p ? s - SROWS3 * 16 : s;
            const int row = s2 >> 4;         // 0..11
            const int c4  = s2 & 15;         // f4 slot within row
            const int g   = h0 + row - PAD;  // global row
            float4 val = make_float4(0.f, 0.f, 0.f, 0.f);
            if ((unsigned)g < (unsigned)H)
                val = *(const float4*)((p ? vp : kp) + g * W + c4 * 4);
            float* dst = (p ? &sv[0][0] : &sk[0][0]) + row * SCOLS + 2 + c4 * 4;
            *(float2*)dst       = make_float2(val.x, val.y);
            *(float2*)(dst + 2) = make_float2(val.z, val.w);
        }
    }
    // ---- halo ring zero: cols {0,1},{66..71} of all 12 rows, both planes ----
    if (t < 2 * SROWS3 * 4) {          // 96
        const int p   = (t >= SROWS3 * 4);
        const int s   = p ? t - SROWS3 * 4 : t;
        const int row = s >> 2;              // 0..11
        const int e   = s & 3;               // 0 -> col 0; 1..3 -> 66,68,70
        const int col = (e == 0) ? 0 : (64 + 2 * e);
        float* dst = (p ? &sv[0][0] : &sk[0][0]) + row * SCOLS + col;
        *(float2*)dst = make_float2(0.f, 0.f);
    }
    __syncthreads();

    const float qe[2] = {qv.x, qv.y};   // already * log2(e)

    const bool is_h = (c < (C / 2));
    const float* rp = is_h ? (rel_h + c * K) : (rel_w + (c - C / 2) * K);
    float r[K];
#pragma unroll
    for (int u2 = 0; u2 < K; ++u2) r[u2] = rp[u2];

    float den[2] = {0.f, 0.f};
    float num[2] = {0.f, 0.f};

    // px at global col w0+px; tap j reads LDS col (w0+px)+j  (interior at +2)
    if (is_h) {
#pragma unroll
        for (int i = 0; i < K; ++i) {
            const float2 k0 = *(const float2*)&sk[lr + i][w0];
            const float2 k1 = *(const float2*)&sk[lr + i][w0 + 2];
            const float2 k2 = *(const float2*)&sk[lr + i][w0 + 4];
            const float2 v0 = *(const float2*)&sv[lr + i][w0];
            const float2 v1 = *(const float2*)&sv[lr + i][w0 + 2];
            const float2 v2 = *(const float2*)&sv[lr + i][w0 + 4];
            const float kt[6] = {k0.x, k0.y, k1.x, k1.y, k2.x, k2.y};
            const float vt[6] = {v0.x, v0.y, v1.x, v1.y, v2.x, v2.y};
            const float qri0 = qe[0] * r[i];
            const float qri1 = qe[1] * r[i];
#pragma unroll
            for (int j = 0; j < K; ++j) {
                const float e0 = fast_exp2(fmaf(qe[0], kt[j], qri0));
                den[0] += e0;
                num[0] = fmaf(e0, vt[j], num[0]);
                const float e1 = fast_exp2(fmaf(qe[1], kt[j + 1], qri1));
                den[1] += e1;
                num[1] = fmaf(e1, vt[j + 1], num[1]);
            }
        }
    } else {
#pragma unroll
        for (int i = 0; i < K; ++i) {
            const float2 k0 = *(const float2*)&sk[lr + i][w0];
            const float2 k1 = *(const float2*)&sk[lr + i][w0 + 2];
            const float2 k2 = *(const float2*)&sk[lr + i][w0 + 4];
            const float2 v0 = *(const float2*)&sv[lr + i][w0];
            const float2 v1 = *(const float2*)&sv[lr + i][w0 + 2];
            const float2 v2 = *(const float2*)&sv[lr + i][w0 + 4];
            const float kt[6] = {k0.x, k0.y, k1.x, k1.y, k2.x, k2.y};
            const float vt[6] = {v0.x, v0.y, v1.x, v1.y, v2.x, v2.y};
#pragma unroll
            for (int j = 0; j < K; ++j) {
                const float qrj0 = qe[0] * r[j];
                const float qrj1 = qe[1] * r[j];
                const float e0 = fast_exp2(fmaf(qe[0], kt[j], qrj0));
                den[0] += e0;
                num[0] = fmaf(e0, vt[j], num[0]);
                const float e1 = fast_exp2(fmaf(qe[1], kt[j + 1], qrj1));
                den[1] += e1;
                num[1] = fmaf(e1, vt[j + 1], num[1]);
            }
        }
    }

    f32x2 o;
    o.x = num[0] * __builtin_amdgcn_rcpf(den[0]);
    o.y = num[1] * __builtin_amdgcn_rcpf(den[1]);
    // nt store: out is never re-read on device; keep it out of L2
    __builtin_nontemporal_store(o, (f32x2*)(out + pl * HW + h * W + w0));
}

// ---------------------------------------------------------------------------
extern "C" void kernel_launch(void* const* d_in, const int* in_sizes, int n_in,
                              void* d_out, int out_size, void* d_ws, size_t ws_size,
                              hipStream_t stream)
{
    const float* x     = (const float*)d_in[0];
    const float* Wq    = (const float*)d_in[1];
    const float* Wk    = (const float*)d_in[2];
    const float* Wv    = (const float*)d_in[3];
    const float* rel_h = (const float*)d_in[4];
    const float* rel_w = (const float*)d_in[5];

    float* qb = (float*)d_ws;        // [B,C,64,64]  8 MB  (q pre-scaled)
    float* kb = qb + TOT;            // [B,C,64,64]  8 MB
    float* vb = kb + TOT;            // [B,C,64,64]  8 MB

    qkv_mfma<<<B * 128, 256, 0, stream>>>(x, Wq, Wk, Wv, qb, kb, vb);

    attn_kernel<<<B * C * 8, 256, 0, stream>>>(qb, kb, vb, rel_h, rel_w,
                                               (float*)d_out);
}

// Round 26
// 25.829 us; speedup vs baseline: 1.1198x; 1.0155x over previous
//
#include <hip/hip_runtime.h>
#include <hip/hip_bf16.h>

// Problem constants (from reference)
#define B 8
#define C 64
#define H 64
#define W 64
#define K 5
#define PAD 2
#define HW (H * W)          // 4096
#define CHW (C * HW)        // 262144
#define TOT (B * CHW)       // 2097152

// attn tiling (r21 shape): block = 8 rows x 64 cols; 2 px/thread; 4096 blocks
#define TROWS3 8
#define SROWS3 (TROWS3 + 2 * PAD)  // 12 staged rows
#define SCOLS 72                   // 64 + 2*PAD padded to 72 (16B row align)

#define LOG2E 1.44269504088896340736f

typedef __attribute__((ext_vector_type(8))) short short8;   // 8 bf16 = 4 VGPR
typedef __attribute__((ext_vector_type(4))) float f32x4;    // mfma accum
typedef __attribute__((ext_vector_type(2))) float f32x2;    // nt-load/store

// native bf16 conversion (RNE; pairs lower to v_cvt_pk_bf16_f32)
__device__ inline unsigned short f2bf(float f) {
    __hip_bfloat16 h = __float2bfloat16(f);
    return *(unsigned short*)&h;
}
__device__ inline float bf2f(unsigned short u) {
    return __uint_as_float(((unsigned)u) << 16);
}

// raw v_exp_f32 (single instruction; inputs in [-40,40])
__device__ inline float fast_exp2(float x) {
    return __builtin_amdgcn_exp2f(x);
}

// ---------------------------------------------------------------------------
// Pass 1 (v12): qkv MFMA GEMM — byte-identical to r25 (best: 26.2 us).
// A-frag prep hoisted above the stage; q pre-scaled by log2(e) in epilogue.
// ---------------------------------------------------------------------------
__global__ __launch_bounds__(256) void qkv_mfma(
    const float* __restrict__ x,
    const float* __restrict__ Wq,
    const float* __restrict__ Wk,
    const float* __restrict__ Wv,
    float* __restrict__ qb, float* __restrict__ kb, float* __restrict__ vb)
{
    __shared__ unsigned short sxh[32][72];   // [n][k], 4.6 KB
    __shared__ unsigned short sxl[32][72];

    const int bid = blockIdx.x;
    const int b   = bid & 7;             // XCD co-residency: batch = XCD
    const int n0  = (bid >> 3) * 32;     // hw base (128 chunks per batch)
    const int t   = threadIdx.x;

    const int lane = t & 63;
    const int wv   = __builtin_amdgcn_readfirstlane(t >> 6);  // wave id 0..3
    const int lr   = lane & 15;          // tile row (A) / col (B,D)
    const int lk   = (lane >> 4) * 8;    // k-group base

    // ---- A fragments FIRST (overlaps the x stage-load latency below) ----
    short8 ah[3][2], al[3][2];
#pragma unroll
    for (int ot = 0; ot < 3; ++ot) {
        const int tile = wv * 3 + ot;            // 0..11
        const int m    = tile >> 2;              // 0=q,1=k,2=v
        const int ol0  = (tile & 3) * 16;        // o base within matrix
        const float* Wm = (m == 0) ? Wq : (m == 1) ? Wk : Wv;
        const float* wrow = Wm + (ol0 + lr) * 64;
#pragma unroll
        for (int ks = 0; ks < 2; ++ks) {
            const float4 w0 = *(const float4*)(wrow + lk + ks * 32);
            const float4 w1 = *(const float4*)(wrow + lk + ks * 32 + 4);
            const float wv8[8] = {w0.x, w0.y, w0.z, w0.w,
                                  w1.x, w1.y, w1.z, w1.w};
            short8 hi, lo;
#pragma unroll
            for (int j = 0; j < 8; ++j) {
                const unsigned short hh = f2bf(wv8[j]);
                hi[j] = (short)hh;
                lo[j] = (short)f2bf(wv8[j] - bf2f(hh));
            }
            ah[ot][ks] = hi;
            al[ot][ks] = lo;
        }
    }

    // ---- stage + convert x: 512 float4, 2 per thread, coalesced ----
    const float* xb = x + b * CHW;
#pragma unroll
    for (int i = 0; i < 2; ++i) {
        const int flat = t + i * 256;        // 0..511
        const int k    = flat >> 3;          // 8 float4 per k-row of 32
        const int n4   = (flat & 7) << 2;
        const float4 v = *(const float4*)(xb + k * HW + n0 + n4);
        const float vv[4] = {v.x, v.y, v.z, v.w};
#pragma unroll
        for (int j = 0; j < 4; ++j) {
            const unsigned short h = f2bf(vv[j]);
            sxh[n4 + j][k] = h;
            sxl[n4 + j][k] = f2bf(vv[j] - bf2f(h));
        }
    }
    __syncthreads();

    f32x4 acc[3][2];
#pragma unroll
    for (int ot = 0; ot < 3; ++ot)
#pragma unroll
        for (int nt = 0; nt < 2; ++nt) acc[ot][nt] = (f32x4)0.f;

#pragma unroll
    for (int nt = 0; nt < 2; ++nt) {
        const short8 bh0 = *(const short8*)&sxh[nt * 16 + lr][lk];
        const short8 bh1 = *(const short8*)&sxh[nt * 16 + lr][32 + lk];
        const short8 bl0 = *(const short8*)&sxl[nt * 16 + lr][lk];
        const short8 bl1 = *(const short8*)&sxl[nt * 16 + lr][32 + lk];
#pragma unroll
        for (int ot = 0; ot < 3; ++ot) {
            f32x4 d = acc[ot][nt];
            d = __builtin_amdgcn_mfma_f32_16x16x32_bf16(ah[ot][0], bh0, d, 0, 0, 0);
            d = __builtin_amdgcn_mfma_f32_16x16x32_bf16(ah[ot][1], bh1, d, 0, 0, 0);
            d = __builtin_amdgcn_mfma_f32_16x16x32_bf16(ah[ot][0], bl0, d, 0, 0, 0);
            d = __builtin_amdgcn_mfma_f32_16x16x32_bf16(ah[ot][1], bl1, d, 0, 0, 0);
            d = __builtin_amdgcn_mfma_f32_16x16x32_bf16(al[ot][0], bh0, d, 0, 0, 0);
            d = __builtin_amdgcn_mfma_f32_16x16x32_bf16(al[ot][1], bh1, d, 0, 0, 0);
            acc[ot][nt] = d;
        }
    }

#pragma unroll
    for (int ot = 0; ot < 3; ++ot) {
        const int tile = wv * 3 + ot;
        const int m    = tile >> 2;
        const int ol0  = (tile & 3) * 16;
        float* ob = (m == 0) ? qb : (m == 1) ? kb : vb;
        const float scale = (m == 0) ? LOG2E : 1.0f;   // q pre-scaled for exp2
        float* basep = ob + b * CHW + ol0 * HW + n0;
#pragma unroll
        for (int nt = 0; nt < 2; ++nt)
#pragma unroll
            for (int r = 0; r < 4; ++r) {
                const int orow = (lane >> 4) * 4 + r;
                basep[orow * HW + nt * 16 + lr] = acc[ot][nt][r] * scale;
            }
    }
}

// ---------------------------------------------------------------------------
// Pass 2 (v13): attn — r25 structure with two micro-fixes:
// (1) is_w branch: qrj[] bias products hoisted OUT of the i/j loops
//     (were recomputed per tap: 50 extra VALU/thread on half the blocks);
// (2) rel_h/rel_w bias load hoisted ABOVE the stage (overlaps latency).
// Everything else (nt q-load/out-store, f4 stage, pow-2 mapping, raw
// v_exp) identical to r25.
// ---------------------------------------------------------------------------
__global__ __launch_bounds__(256) void attn_kernel(
    const float* __restrict__ qb,
    const float* __restrict__ kb,
    const float* __restrict__ vb,
    const float* __restrict__ rel_h,
    const float* __restrict__ rel_w,
    float* __restrict__ out)
{
    __shared__ __align__(16) float sk[SROWS3][SCOLS];   // 3.5 KB
    __shared__ __align__(16) float sv[SROWS3][SCOLS];   // 3.5 KB

    const int bid = blockIdx.x;
    const int b   = bid & 7;           // XCD co-residency: batch = XCD
    const int u   = bid >> 3;          // 0..511: c*8 + rowtile
    const int c   = u >> 3;
    const int pl  = b * C + c;
    const int h0  = (u & 7) * TROWS3;
    const int t   = threadIdx.x;

    const int lr = t >> 5;             // local row 0..7
    const int w0 = (t & 31) << 1;      // col base 0,2,..,62 (2 px)
    const int h  = h0 + lr;

    // hoisted loads: q (nt, pre-scaled by log2e) and bias row — both
    // overlap the stage latency below
    const f32x2 qv = __builtin_nontemporal_load(
        (const f32x2*)(qb + pl * HW + h * W + w0));
    const bool is_h = (c < (C / 2));
    const float* rp = is_h ? (rel_h + c * K) : (rel_w + (c - C / 2) * K);
    float r[K];
#pragma unroll
    for (int u2 = 0; u2 < K; ++u2) r[u2] = rp[u2];

    const float* kp = kb + pl * HW;
    const float* vp = vb + pl * HW;

    // ---- stage interior: 2 planes * (12 rows x 16 f4) = 384 slots ----
#pragma unroll
    for (int i = 0; i < 2; ++i) {
        const int s = t + i * 256;           // 0..511
        if (s < 2 * SROWS3 * 16) {           // 384
            const int p   = (s >= SROWS3 * 16);
            const int s2  = p ? s - SROWS3 * 16 : s;
            const int row = s2 >> 4;         // 0..11
            const int c4  = s2 & 15;         // f4 slot within row
            const int g   = h0 + row - PAD;  // global row
            float4 val = make_float4(0.f, 0.f, 0.f, 0.f);
            if ((unsigned)g < (unsigned)H)
                val = *(const float4*)((p ? vp : kp) + g * W + c4 * 4);
            float* dst = (p ? &sv[0][0] : &sk[0][0]) + row * SCOLS + 2 + c4 * 4;
            *(float2*)dst       = make_float2(val.x, val.y);
            *(float2*)(dst + 2) = make_float2(val.z, val.w);
        }
    }
    // ---- halo ring zero: cols {0,1},{66..71} of all 12 rows, both planes ----
    if (t < 2 * SROWS3 * 4) {          // 96
        const int p   = (t >= SROWS3 * 4);
        const int s   = p ? t - SROWS3 * 4 : t;
        const int row = s >> 2;              // 0..11
        const int e   = s & 3;               // 0 -> col 0; 1..3 -> 66,68,70
        const int col = (e == 0) ? 0 : (64 + 2 * e);
        float* dst = (p ? &sv[0][0] : &sk[0][0]) + row * SCOLS + col;
        *(float2*)dst = make_float2(0.f, 0.f);
    }
    __syncthreads();

    const float qe[2] = {qv.x, qv.y};   // already * log2(e)

    float den[2] = {0.f, 0.f};
    float num[2] = {0.f, 0.f};

    // px at global col w0+px; tap j reads LDS col (w0+px)+j  (interior at +2)
    if (is_h) {
#pragma unroll
        for (int i = 0; i < K; ++i) {
            const float2 k0 = *(const float2*)&sk[lr + i][w0];
            const float2 k1 = *(const float2*)&sk[lr + i][w0 + 2];
            const float2 k2 = *(const float2*)&sk[lr + i][w0 + 4];
            const float2 v0 = *(const float2*)&sv[lr + i][w0];
            const float2 v1 = *(const float2*)&sv[lr + i][w0 + 2];
            const float2 v2 = *(const float2*)&sv[lr + i][w0 + 4];
            const float kt[6] = {k0.x, k0.y, k1.x, k1.y, k2.x, k2.y};
            const float vt[6] = {v0.x, v0.y, v1.x, v1.y, v2.x, v2.y};
            const float qri0 = qe[0] * r[i];
            const float qri1 = qe[1] * r[i];
#pragma unroll
            for (int j = 0; j < K; ++j) {
                const float e0 = fast_exp2(fmaf(qe[0], kt[j], qri0));
                den[0] += e0;
                num[0] = fmaf(e0, vt[j], num[0]);
                const float e1 = fast_exp2(fmaf(qe[1], kt[j + 1], qri1));
                den[1] += e1;
                num[1] = fmaf(e1, vt[j + 1], num[1]);
            }
        }
    } else {
        // hoisted bias products (were recomputed per tap in r25)
        float qrj0[K], qrj1[K];
#pragma unroll
        for (int j = 0; j < K; ++j) {
            qrj0[j] = qe[0] * r[j];
            qrj1[j] = qe[1] * r[j];
        }
#pragma unroll
        for (int i = 0; i < K; ++i) {
            const float2 k0 = *(const float2*)&sk[lr + i][w0];
            const float2 k1 = *(const float2*)&sk[lr + i][w0 + 2];
            const float2 k2 = *(const float2*)&sk[lr + i][w0 + 4];
            const float2 v0 = *(const float2*)&sv[lr + i][w0];
            const float2 v1 = *(const float2*)&sv[lr + i][w0 + 2];
            const float2 v2 = *(const float2*)&sv[lr + i][w0 + 4];
            const float kt[6] = {k0.x, k0.y, k1.x, k1.y, k2.x, k2.y};
            const float vt[6] = {v0.x, v0.y, v1.x, v1.y, v2.x, v2.y};
#pragma unroll
            for (int j = 0; j < K; ++j) {
                const float e0 = fast_exp2(fmaf(qe[0], kt[j], qrj0[j]));
                den[0] += e0;
                num[0] = fmaf(e0, vt[j], num[0]);
                const float e1 = fast_exp2(fmaf(qe[1], kt[j + 1], qrj1[j]));
                den[1] += e1;
                num[1] = fmaf(e1, vt[j + 1], num[1]);
            }
        }
    }

    f32x2 o;
    o.x = num[0] * __builtin_amdgcn_rcpf(den[0]);
    o.y = num[1] * __builtin_amdgcn_rcpf(den[1]);
    // nt store: out is never re-read on device; keep it out of L2
    __builtin_nontemporal_store(o, (f32x2*)(out + pl * HW + h * W + w0));
}

// ---------------------------------------------------------------------------
extern "C" void kernel_launch(void* const* d_in, const int* in_sizes, int n_in,
                              void* d_out, int out_size, void* d_ws, size_t ws_size,
                              hipStream_t stream)
{
    const float* x     = (const float*)d_in[0];
    const float* Wq    = (const float*)d_in[1];
    const float* Wk    = (const float*)d_in[2];
    const float* Wv    = (const float*)d_in[3];
    const float* rel_h = (const float*)d_in[4];
    const float* rel_w = (const float*)d_in[5];

    float* qb = (float*)d_ws;        // [B,C,64,64]  8 MB  (q pre-scaled)
    float* kb = qb + TOT;            // [B,C,64,64]  8 MB
    float* vb = kb + TOT;            // [B,C,64,64]  8 MB

    qkv_mfma<<<B * 128, 256, 0, stream>>>(x, Wq, Wk, Wv, qb, kb, vb);

    attn_kernel<<<B * C * 8, 256, 0, stream>>>(qb, kb, vb, rel_h, rel_w,
                                               (float*)d_out);
}

// Round 27
// 25.538 us; speedup vs baseline: 1.1326x; 1.0114x over previous
//
#include <hip/hip_runtime.h>
#include <hip/hip_bf16.h>

// Problem constants (from reference)
#define B 8
#define C 64
#define H 64
#define W 64
#define K 5
#define PAD 2
#define HW (H * W)          // 4096
#define CHW (C * HW)        // 262144
#define TOT (B * CHW)       // 2097152

// attn tiling (r21 shape): block = 8 rows x 64 cols; 2 px/thread; 4096 blocks
#define TROWS3 8
#define SROWS3 (TROWS3 + 2 * PAD)  // 12 staged rows
#define SCOLS 72                   // 64 + 2*PAD padded to 72 (16B row align)

#define LOG2E 1.44269504088896340736f

typedef __attribute__((ext_vector_type(8))) short short8;   // 8 bf16 = 4 VGPR
typedef __attribute__((ext_vector_type(4))) float f32x4;    // mfma accum
typedef __attribute__((ext_vector_type(2))) float f32x2;    // packed fp32

// native bf16 conversion (RNE; pairs lower to v_cvt_pk_bf16_f32)
__device__ inline unsigned short f2bf(float f) {
    __hip_bfloat16 h = __float2bfloat16(f);
    return *(unsigned short*)&h;
}
__device__ inline float bf2f(unsigned short u) {
    return __uint_as_float(((unsigned)u) << 16);
}

// raw v_exp_f32 (single instruction; inputs in [-40,40])
__device__ inline float fast_exp2(float x) {
    return __builtin_amdgcn_exp2f(x);
}

// ---------------------------------------------------------------------------
// Pass 1 (v12): qkv MFMA GEMM — byte-identical to r25/r26 (best).
// A-frag prep hoisted above the stage; q pre-scaled by log2(e) in epilogue.
// ---------------------------------------------------------------------------
__global__ __launch_bounds__(256) void qkv_mfma(
    const float* __restrict__ x,
    const float* __restrict__ Wq,
    const float* __restrict__ Wk,
    const float* __restrict__ Wv,
    float* __restrict__ qb, float* __restrict__ kb, float* __restrict__ vb)
{
    __shared__ unsigned short sxh[32][72];   // [n][k], 4.6 KB
    __shared__ unsigned short sxl[32][72];

    const int bid = blockIdx.x;
    const int b   = bid & 7;             // XCD co-residency: batch = XCD
    const int n0  = (bid >> 3) * 32;     // hw base (128 chunks per batch)
    const int t   = threadIdx.x;

    const int lane = t & 63;
    const int wv   = __builtin_amdgcn_readfirstlane(t >> 6);  // wave id 0..3
    const int lr   = lane & 15;          // tile row (A) / col (B,D)
    const int lk   = (lane >> 4) * 8;    // k-group base

    // ---- A fragments FIRST (overlaps the x stage-load latency below) ----
    short8 ah[3][2], al[3][2];
#pragma unroll
    for (int ot = 0; ot < 3; ++ot) {
        const int tile = wv * 3 + ot;            // 0..11
        const int m    = tile >> 2;              // 0=q,1=k,2=v
        const int ol0  = (tile & 3) * 16;        // o base within matrix
        const float* Wm = (m == 0) ? Wq : (m == 1) ? Wk : Wv;
        const float* wrow = Wm + (ol0 + lr) * 64;
#pragma unroll
        for (int ks = 0; ks < 2; ++ks) {
            const float4 w0 = *(const float4*)(wrow + lk + ks * 32);
            const float4 w1 = *(const float4*)(wrow + lk + ks * 32 + 4);
            const float wv8[8] = {w0.x, w0.y, w0.z, w0.w,
                                  w1.x, w1.y, w1.z, w1.w};
            short8 hi, lo;
#pragma unroll
            for (int j = 0; j < 8; ++j) {
                const unsigned short hh = f2bf(wv8[j]);
                hi[j] = (short)hh;
                lo[j] = (short)f2bf(wv8[j] - bf2f(hh));
            }
            ah[ot][ks] = hi;
            al[ot][ks] = lo;
        }
    }

    // ---- stage + convert x: 512 float4, 2 per thread, coalesced ----
    const float* xb = x + b * CHW;
#pragma unroll
    for (int i = 0; i < 2; ++i) {
        const int flat = t + i * 256;        // 0..511
        const int k    = flat >> 3;          // 8 float4 per k-row of 32
        const int n4   = (flat & 7) << 2;
        const float4 v = *(const float4*)(xb + k * HW + n0 + n4);
        const float vv[4] = {v.x, v.y, v.z, v.w};
#pragma unroll
        for (int j = 0; j < 4; ++j) {
            const unsigned short h = f2bf(vv[j]);
            sxh[n4 + j][k] = h;
            sxl[n4 + j][k] = f2bf(vv[j] - bf2f(h));
        }
    }
    __syncthreads();

    f32x4 acc[3][2];
#pragma unroll
    for (int ot = 0; ot < 3; ++ot)
#pragma unroll
        for (int nt = 0; nt < 2; ++nt) acc[ot][nt] = (f32x4)0.f;

#pragma unroll
    for (int nt = 0; nt < 2; ++nt) {
        const short8 bh0 = *(const short8*)&sxh[nt * 16 + lr][lk];
        const short8 bh1 = *(const short8*)&sxh[nt * 16 + lr][32 + lk];
        const short8 bl0 = *(const short8*)&sxl[nt * 16 + lr][lk];
        const short8 bl1 = *(const short8*)&sxl[nt * 16 + lr][32 + lk];
#pragma unroll
        for (int ot = 0; ot < 3; ++ot) {
            f32x4 d = acc[ot][nt];
            d = __builtin_amdgcn_mfma_f32_16x16x32_bf16(ah[ot][0], bh0, d, 0, 0, 0);
            d = __builtin_amdgcn_mfma_f32_16x16x32_bf16(ah[ot][1], bh1, d, 0, 0, 0);
            d = __builtin_amdgcn_mfma_f32_16x16x32_bf16(ah[ot][0], bl0, d, 0, 0, 0);
            d = __builtin_amdgcn_mfma_f32_16x16x32_bf16(ah[ot][1], bl1, d, 0, 0, 0);
            d = __builtin_amdgcn_mfma_f32_16x16x32_bf16(al[ot][0], bh0, d, 0, 0, 0);
            d = __builtin_amdgcn_mfma_f32_16x16x32_bf16(al[ot][1], bh1, d, 0, 0, 0);
            acc[ot][nt] = d;
        }
    }

#pragma unroll
    for (int ot = 0; ot < 3; ++ot) {
        const int tile = wv * 3 + ot;
        const int m    = tile >> 2;
        const int ol0  = (tile & 3) * 16;
        float* ob = (m == 0) ? qb : (m == 1) ? kb : vb;
        const float scale = (m == 0) ? LOG2E : 1.0f;   // q pre-scaled for exp2
        float* basep = ob + b * CHW + ol0 * HW + n0;
#pragma unroll
        for (int nt = 0; nt < 2; ++nt)
#pragma unroll
            for (int r = 0; r < 4; ++r) {
                const int orow = (lane >> 4) * 4 + r;
                basep[orow * HW + nt * 16 + lr] = acc[ot][nt][r] * scale;
            }
    }
}

// ---------------------------------------------------------------------------
// Pass 2 (v14): attn — r26 structure with PACKED-FP32 inner loop: den/num/
// logit arithmetic on f32x2 ext-vectors via __builtin_elementwise_fma so
// the px0/px1 streams lower to v_pk_fma_f32 / v_pk_add_f32 (VOP3P, 2 fp32
// ops per instruction) instead of 2x scalar VALU.  Per tap-pair: 8 scalar
// VALU -> 1 pk_fma + 2 v_exp + 1 pk_add + 1 pk_fma.  Everything else
// (nt hints, f4 stage, pow-2 mapping, grid, swizzle) identical to r26.
// ---------------------------------------------------------------------------
__global__ __launch_bounds__(256) void attn_kernel(
    const float* __restrict__ qb,
    const float* __restrict__ kb,
    const float* __restrict__ vb,
    const float* __restrict__ rel_h,
    const float* __restrict__ rel_w,
    float* __restrict__ out)
{
    __shared__ __align__(16) float sk[SROWS3][SCOLS];   // 3.5 KB
    __shared__ __align__(16) float sv[SROWS3][SCOLS];   // 3.5 KB

    const int bid = blockIdx.x;
    const int b   = bid & 7;           // XCD co-residency: batch = XCD
    const int u   = bid >> 3;          // 0..511: c*8 + rowtile
    const int c   = u >> 3;
    const int pl  = b * C + c;
    const int h0  = (u & 7) * TROWS3;
    const int t   = threadIdx.x;

    const int lr = t >> 5;             // local row 0..7
    const int w0 = (t & 31) << 1;      // col base 0,2,..,62 (2 px)
    const int h  = h0 + lr;

    // hoisted loads: q (nt, pre-scaled by log2e) and bias row — both
    // overlap the stage latency below
    const f32x2 qe2 = __builtin_nontemporal_load(
        (const f32x2*)(qb + pl * HW + h * W + w0));
    const bool is_h = (c < (C / 2));
    const float* rp = is_h ? (rel_h + c * K) : (rel_w + (c - C / 2) * K);
    float r[K];
#pragma unroll
    for (int u2 = 0; u2 < K; ++u2) r[u2] = rp[u2];

    const float* kp = kb + pl * HW;
    const float* vp = vb + pl * HW;

    // ---- stage interior: 2 planes * (12 rows x 16 f4) = 384 slots ----
#pragma unroll
    for (int i = 0; i < 2; ++i) {
        const int s = t + i * 256;           // 0..511
        if (s < 2 * SROWS3 * 16) {           // 384
            const int p   = (s >= SROWS3 * 16);
            const int s2  = p ? s - SROWS3 * 16 : s;
            const int row = s2 >> 4;         // 0..11
            const int c4  = s2 & 15;         // f4 slot within row
            const int g   = h0 + row - PAD;  // global row
            float4 val = make_float4(0.f, 0.f, 0.f, 0.f);
            if ((unsigned)g < (unsigned)H)
                val = *(const float4*)((p ? vp : kp) + g * W + c4 * 4);
            float* dst = (p ? &sv[0][0] : &sk[0][0]) + row * SCOLS + 2 + c4 * 4;
            *(float2*)dst       = make_float2(val.x, val.y);
            *(float2*)(dst + 2) = make_float2(val.z, val.w);
        }
    }
    // ---- halo ring zero: cols {0,1},{66..71} of all 12 rows, both planes ----
    if (t < 2 * SROWS3 * 4) {          // 96
        const int p   = (t >= SROWS3 * 4);
        const int s   = p ? t - SROWS3 * 4 : t;
        const int row = s >> 2;              // 0..11
        const int e   = s & 3;               // 0 -> col 0; 1..3 -> 66,68,70
        const int col = (e == 0) ? 0 : (64 + 2 * e);
        float* dst = (p ? &sv[0][0] : &sk[0][0]) + row * SCOLS + col;
        *(float2*)dst = make_float2(0.f, 0.f);
    }
    __syncthreads();

    f32x2 den = {0.f, 0.f};
    f32x2 num = {0.f, 0.f};

    // px at global col w0+px; tap j reads LDS col (w0+px)+j  (interior at +2)
    if (is_h) {
#pragma unroll
        for (int i = 0; i < K; ++i) {
            const float2 k0 = *(const float2*)&sk[lr + i][w0];
            const float2 k1 = *(const float2*)&sk[lr + i][w0 + 2];
            const float2 k2 = *(const float2*)&sk[lr + i][w0 + 4];
            const float2 v0 = *(const float2*)&sv[lr + i][w0];
            const float2 v1 = *(const float2*)&sv[lr + i][w0 + 2];
            const float2 v2 = *(const float2*)&sv[lr + i][w0 + 4];
            const float kt[6] = {k0.x, k0.y, k1.x, k1.y, k2.x, k2.y};
            const float vt[6] = {v0.x, v0.y, v1.x, v1.y, v2.x, v2.y};
            const f32x2 qri = qe2 * r[i];                 // v_pk_mul
#pragma unroll
            for (int j = 0; j < K; ++j) {
                const f32x2 ktp = {kt[j], kt[j + 1]};
                const f32x2 vtp = {vt[j], vt[j + 1]};
                const f32x2 l = __builtin_elementwise_fma(qe2, ktp, qri);
                const f32x2 e = {fast_exp2(l.x), fast_exp2(l.y)};
                den += e;                                  // v_pk_add
                num = __builtin_elementwise_fma(e, vtp, num);  // v_pk_fma
            }
        }
    } else {
        f32x2 qrj[K];
#pragma unroll
        for (int j = 0; j < K; ++j) qrj[j] = qe2 * r[j];   // hoisted pk_mul
#pragma unroll
        for (int i = 0; i < K; ++i) {
            const float2 k0 = *(const float2*)&sk[lr + i][w0];
            const float2 k1 = *(const float2*)&sk[lr + i][w0 + 2];
            const float2 k2 = *(const float2*)&sk[lr + i][w0 + 4];
            const float2 v0 = *(const float2*)&sv[lr + i][w0];
            const float2 v1 = *(const float2*)&sv[lr + i][w0 + 2];
            const float2 v2 = *(const float2*)&sv[lr + i][w0 + 4];
            const float kt[6] = {k0.x, k0.y, k1.x, k1.y, k2.x, k2.y};
            const float vt[6] = {v0.x, v0.y, v1.x, v1.y, v2.x, v2.y};
#pragma unroll
            for (int j = 0; j < K; ++j) {
                const f32x2 ktp = {kt[j], kt[j + 1]};
                const f32x2 vtp = {vt[j], vt[j + 1]};
                const f32x2 l = __builtin_elementwise_fma(qe2, ktp, qrj[j]);
                const f32x2 e = {fast_exp2(l.x), fast_exp2(l.y)};
                den += e;
                num = __builtin_elementwise_fma(e, vtp, num);
            }
        }
    }

    f32x2 o;
    o.x = num.x * __builtin_amdgcn_rcpf(den.x);
    o.y = num.y * __builtin_amdgcn_rcpf(den.y);
    // nt store: out is never re-read on device; keep it out of L2
    __builtin_nontemporal_store(o, (f32x2*)(out + pl * HW + h * W + w0));
}

// ---------------------------------------------------------------------------
extern "C" void kernel_launch(void* const* d_in, const int* in_sizes, int n_in,
                              void* d_out, int out_size, void* d_ws, size_t ws_size,
                              hipStream_t stream)
{
    const float* x     = (const float*)d_in[0];
    const float* Wq    = (const float*)d_in[1];
    const float* Wk    = (const float*)d_in[2];
    const float* Wv    = (const float*)d_in[3];
    const float* rel_h = (const float*)d_in[4];
    const float* rel_w = (const float*)d_in[5];

    float* qb = (float*)d_ws;        // [B,C,64,64]  8 MB  (q pre-scaled)
    float* kb = qb + TOT;            // [B,C,64,64]  8 MB
    float* vb = kb + TOT;            // [B,C,64,64]  8 MB

    qkv_mfma<<<B * 128, 256, 0, stream>>>(x, Wq, Wk, Wv, qb, kb, vb);

    attn_kernel<<<B * C * 8, 256, 0, stream>>>(qb, kb, vb, rel_h, rel_w,
                                               (float*)d_out);
}